// Round 17
// baseline (400.138 us; speedup 1.0000x reference)
//
#include <hip/hip_runtime.h>
#include <hip/hip_fp16.h>

#define DI __device__ __forceinline__

typedef __attribute__((ext_vector_type(4))) float f32x4;
typedef __attribute__((ext_vector_type(8))) _Float16 f16x8;
typedef __attribute__((ext_vector_type(8))) short s16x8;
typedef __attribute__((ext_vector_type(4))) short s16x4;

DI unsigned short f2h(float f) { return __half_as_ushort(__float2half(f)); }
DI float h2f(unsigned short u) { return __half2float(__ushort_as_half(u)); }

// operand-swapped: A-operand = weight fragment, B-operand = activation fragment.
// D: lane holds o = l4*4+r (4 consecutive channels), batch-row = l15.
#define MFMA16(A, B, C) (C) = __builtin_amdgcn_mfma_f32_16x16x32_f16((A), (B), (C), 0, 0, 0)

// ---------------------------------------------------------------------------
// Prep: weight-norm fold + diag-scale fold, emitting MFMA-FRAGMENT layout:
//   W'[kj][s][n16][lane(l4*16+l15)][8]; a wave's W-frag load = contiguous 1KB.
// ---------------------------------------------------------------------------
struct PrepArgs {
    const float *adj;
    const float *v0,*g0,*b0,*v1,*g1,*b1,*v2,*g2,*b2,*v3,*g3,*b3,*v4,*g4,*b4;
    unsigned short *w0,*w1,*w2,*w3;
    float *w4, *bias0,*bias1,*bias2,*bias3,*bias4;
};

template <int CIN, int CINPAD>
DI void prep_row(const float* __restrict__ v, const float* __restrict__ g,
                 const float* __restrict__ b, const float* __restrict__ adj,
                 int cout, int use_scale,
                 unsigned short* __restrict__ wout, float* __restrict__ biasout,
                 int ridx, int lane)
{
    const int k = ridx / cout;
    const int o = ridx - k * cout;
    const float* vr = v + (size_t)ridx * CIN;
    float xv[8];
    if (lane * 8 < CIN) {
        const f32x4 p0 = *reinterpret_cast<const f32x4*>(&vr[lane * 8]);
        const f32x4 p1 = *reinterpret_cast<const f32x4*>(&vr[lane * 8 + 4]);
        #pragma unroll
        for (int e = 0; e < 4; e++) { xv[e] = p0[e]; xv[4 + e] = p1[e]; }
    } else {
        #pragma unroll
        for (int e = 0; e < 8; e++) xv[e] = 0.f;
    }
    float ss = 0.f;
    #pragma unroll
    for (int e = 0; e < 8; e++) ss += xv[e] * xv[e];
    #pragma unroll
    for (int off = 32; off >= 1; off >>= 1) ss += __shfl_xor(ss, off, 64);
    float s = g[ridx] / sqrtf(ss);
    float bias = b[ridx];
    if (use_scale) {
        float d = adj[k * 81];            // adj[k][k]
        d = d > 0.f ? d : 0.f;
        s *= d; bias *= d;                // leaky(z)*s == leaky(z*s), s>=0
    }
    if (lane == 0) biasout[ridx] = bias;
    if (lane < CINPAD / 8) {
        unsigned short tmp[8];
        #pragma unroll
        for (int e = 0; e < 8; e++) tmp[e] = f2h(xv[e] * s);
        unsigned short* wj = wout + (size_t)k * cout * CINPAD;
        const int sblk = lane >> 2, l4w = lane & 3;
        const size_t pos = (((size_t)sblk * (cout >> 4) + (o >> 4)) * 64 + l4w * 16 + (o & 15)) * 8;
        *reinterpret_cast<s16x8*>(&wj[pos]) = *reinterpret_cast<const s16x8*>(tmp);
    }
}

DI void prep_w4_row(const float* __restrict__ v, const float* __restrict__ g,
                    const float* __restrict__ b, float* __restrict__ wout,
                    float* __restrict__ biasout, int ridx, int lane)
{
    const float x = v[(size_t)ridx * 64 + lane];
    float ss = x * x;
    #pragma unroll
    for (int off = 32; off >= 1; off >>= 1) ss += __shfl_xor(ss, off, 64);
    const float s = g[ridx] / sqrtf(ss);
    if (lane == 0) biasout[ridx] = b[ridx];
    wout[(size_t)ridx * 64 + lane] = x * s;
}

__global__ __launch_bounds__(256) void prep_kernel(PrepArgs a)
{
    const int bid = blockIdx.x, wave = threadIdx.x >> 6, lane = threadIdx.x & 63;
    if (bid < 10240)      prep_row<480, 512>(a.v0, a.g0, a.b0, a.adj, 512, 1, a.w0, a.bias0, bid * 4 + wave, lane);
    else if (bid < 15360) prep_row<512, 512>(a.v1, a.g1, a.b1, a.adj, 256, 1, a.w1, a.bias1, (bid - 10240) * 4 + wave, lane);
    else if (bid < 17920) prep_row<256, 256>(a.v2, a.g2, a.b2, a.adj, 128, 1, a.w2, a.bias2, (bid - 15360) * 4 + wave, lane);
    else if (bid < 19200) prep_row<128, 128>(a.v3, a.g3, a.b3, a.adj,  64, 0, a.w3, a.bias3, (bid - 17920) * 4 + wave, lane);
    else                  prep_w4_row(a.v4, a.g4, a.b4, a.w4, a.bias4, (bid - 19200) * 4 + wave, lane);
}

// ---------------------------------------------------------------------------
// Mega v9 = mega8 (operand-swapped, fragment-W, XOR swizzle) with M = 32
// rows/block: LDS 32 KB -> 4 blocks/CU -> 8 waves/SIMD (2x occupancy for
// latency hiding). Grid 5120 (64 m-blocks per joint, XCD-chunked).
// ---------------------------------------------------------------------------
struct MegaArgs {
    const float *qp, *pf, *Brff;
    const unsigned short *w0, *w1, *w2, *w3;
    const float *w4, *bias0, *bias1, *bias2, *bias3, *bias4;
    float* out;
};

__global__ __launch_bounds__(512, 8) void mega9_kernel(MegaArgs a)
{
    extern __shared__ __align__(16) unsigned short R0[];   // 16384 shorts = 32 KB
    const int tid = threadIdx.x, wid = tid >> 6, lane = tid & 63;
    const int l15 = lane & 15, l4 = lane >> 4;
    const int bid = blockIdx.x;
    const int swz = (bid & 7) * 640 + (bid >> 3);   // XCD-chunked, bijective (5120%8==0)
    const int kj = swz >> 6;
    const int m0 = (swz & 63) * 32;

    // ---- prologue: h0 = pf + RFF(qp)  -> R0 as [32][512] (480 real + 32 zero-pad)
    {
        const int row = tid >> 4;                 // 0..31 (16 threads per row)
        const int tq  = tid & 15;
        const int gr  = (m0 + row) * 80 + kj;     // batch-major global row
        const float q0 = a.qp[gr * 3 + 0], q1 = a.qp[gr * 3 + 1], q2 = a.qp[gr * 3 + 2];
        #pragma unroll
        for (int i = 0; i < 4; i++) {
            const int c0 = tq * 8 + i * 128;      // multiples of 8, 0..504
            unsigned short o[8];
            if (c0 < 480) {
                const bool issin = (c0 >= 240);
                const int j0 = issin ? (c0 - 240) : c0;
                const f32x4 b0a = *reinterpret_cast<const f32x4*>(&a.Brff[j0]);
                const f32x4 b0b = *reinterpret_cast<const f32x4*>(&a.Brff[j0 + 4]);
                const f32x4 b1a = *reinterpret_cast<const f32x4*>(&a.Brff[240 + j0]);
                const f32x4 b1b = *reinterpret_cast<const f32x4*>(&a.Brff[240 + j0 + 4]);
                const f32x4 b2a = *reinterpret_cast<const f32x4*>(&a.Brff[480 + j0]);
                const f32x4 b2b = *reinterpret_cast<const f32x4*>(&a.Brff[480 + j0 + 4]);
                const f32x4 p0 = __builtin_nontemporal_load(
                    reinterpret_cast<const f32x4*>(&a.pf[(size_t)gr * 480 + c0]));
                const f32x4 p1 = __builtin_nontemporal_load(
                    reinterpret_cast<const f32x4*>(&a.pf[(size_t)gr * 480 + c0 + 4]));
                #pragma unroll
                for (int e = 0; e < 4; e++) {
                    float rev = q0 * b0a[e] + q1 * b1a[e] + q2 * b2a[e];
                    rev -= floorf(rev);           // v_sin/v_cos take revolutions
                    float t = issin ? __builtin_amdgcn_sinf(rev) : __builtin_amdgcn_cosf(rev);
                    o[e] = f2h(p0[e] + t);
                }
                #pragma unroll
                for (int e = 0; e < 4; e++) {
                    float rev = q0 * b0b[e] + q1 * b1b[e] + q2 * b2b[e];
                    rev -= floorf(rev);
                    float t = issin ? __builtin_amdgcn_sinf(rev) : __builtin_amdgcn_cosf(rev);
                    o[4 + e] = f2h(p1[e] + t);
                }
            } else {
                #pragma unroll
                for (int e = 0; e < 8; e++) o[e] = 0;
            }
            const int ck = c0 >> 3;
            *reinterpret_cast<s16x8*>(&R0[row * 512 + ((ck ^ (row & 7)) << 3)]) =
                *reinterpret_cast<const s16x8*>(o);
        }
    }
    __syncthreads();

    // ---- stage 0: h1 = leaky(h0 @ w0^T + b0).  N=512 (wave owns 64 cols), K=512.
    {
        const unsigned short* Wb = a.w0 + (size_t)kj * 262144 + (size_t)(wid * 4) * 512 + lane * 8;
        f32x4 acc[2][4] = {};
        f16x8 bfA[4], bfB[4];
        #pragma unroll
        for (int g = 0; g < 4; g++) bfA[g] = *reinterpret_cast<const f16x8*>(Wb + g * 512);
        #pragma unroll
        for (int ss = 0; ss < 8; ss++) {
            const int s0 = ss * 2, s1 = ss * 2 + 1;
            f16x8 af0[2];
            #pragma unroll
            for (int f = 0; f < 2; f++) {
                const int r = f * 16 + l15;
                af0[f] = *reinterpret_cast<const f16x8*>(&R0[r * 512 + (((s0 * 4 + l4) ^ (r & 7)) << 3)]);
            }
            #pragma unroll
            for (int g = 0; g < 4; g++)
                bfB[g] = *reinterpret_cast<const f16x8*>(Wb + (size_t)s1 * 16384 + g * 512);
            #pragma unroll
            for (int f = 0; f < 2; f++)
                #pragma unroll
                for (int g = 0; g < 4; g++)
                    MFMA16(bfA[g], af0[f], acc[f][g]);
            f16x8 af1[2];
            #pragma unroll
            for (int f = 0; f < 2; f++) {
                const int r = f * 16 + l15;
                af1[f] = *reinterpret_cast<const f16x8*>(&R0[r * 512 + (((s1 * 4 + l4) ^ (r & 7)) << 3)]);
            }
            if (ss < 7) {
                #pragma unroll
                for (int g = 0; g < 4; g++)
                    bfA[g] = *reinterpret_cast<const f16x8*>(Wb + (size_t)(s0 + 2) * 16384 + g * 512);
            }
            #pragma unroll
            for (int f = 0; f < 2; f++)
                #pragma unroll
                for (int g = 0; g < 4; g++)
                    MFMA16(bfB[g], af1[f], acc[f][g]);
        }
        __syncthreads();                          // all h0 reads done
        #pragma unroll
        for (int g = 0; g < 4; g++) {
            const f32x4 bv = *reinterpret_cast<const f32x4*>(
                &a.bias0[kj * 512 + wid * 64 + g * 16 + l4 * 4]);
            const int o = wid * 64 + g * 16 + l4 * 4;
            #pragma unroll
            for (int f = 0; f < 2; f++) {
                unsigned short o4[4];
                #pragma unroll
                for (int r = 0; r < 4; r++) {
                    float z = acc[f][g][r] + bv[r];
                    z = z >= 0.f ? z : 0.01f * z;
                    o4[r] = f2h(z);
                }
                const int row = f * 16 + l15;
                *reinterpret_cast<s16x4*>(
                    &R0[row * 512 + (((o >> 3) ^ (row & 7)) << 3) + (o & 7)]) =
                    *reinterpret_cast<const s16x4*>(o4);
            }
        }
    }
    __syncthreads();

    // ---- stage 1: h2 = leaky(h1 @ w1^T + b1).  N=256 (wave owns 32), K=512.
    {
        const unsigned short* Wb = a.w1 + (size_t)kj * 131072 + (size_t)(wid * 2) * 512 + lane * 8;
        f32x4 acc[2][2] = {};
        f16x8 bfA[2], bfB[2];
        #pragma unroll
        for (int g = 0; g < 2; g++) bfA[g] = *reinterpret_cast<const f16x8*>(Wb + g * 512);
        #pragma unroll
        for (int ss = 0; ss < 8; ss++) {
            const int s0 = ss * 2, s1 = ss * 2 + 1;
            f16x8 af0[2];
            #pragma unroll
            for (int f = 0; f < 2; f++) {
                const int r = f * 16 + l15;
                af0[f] = *reinterpret_cast<const f16x8*>(&R0[r * 512 + (((s0 * 4 + l4) ^ (r & 7)) << 3)]);
            }
            #pragma unroll
            for (int g = 0; g < 2; g++)
                bfB[g] = *reinterpret_cast<const f16x8*>(Wb + (size_t)s1 * 8192 + g * 512);
            #pragma unroll
            for (int f = 0; f < 2; f++)
                #pragma unroll
                for (int g = 0; g < 2; g++)
                    MFMA16(bfA[g], af0[f], acc[f][g]);
            f16x8 af1[2];
            #pragma unroll
            for (int f = 0; f < 2; f++) {
                const int r = f * 16 + l15;
                af1[f] = *reinterpret_cast<const f16x8*>(&R0[r * 512 + (((s1 * 4 + l4) ^ (r & 7)) << 3)]);
            }
            if (ss < 7) {
                #pragma unroll
                for (int g = 0; g < 2; g++)
                    bfA[g] = *reinterpret_cast<const f16x8*>(Wb + (size_t)(s0 + 2) * 8192 + g * 512);
            }
            #pragma unroll
            for (int f = 0; f < 2; f++)
                #pragma unroll
                for (int g = 0; g < 2; g++)
                    MFMA16(bfB[g], af1[f], acc[f][g]);
        }
        __syncthreads();
        #pragma unroll
        for (int g = 0; g < 2; g++) {
            const f32x4 bv = *reinterpret_cast<const f32x4*>(
                &a.bias1[kj * 256 + wid * 32 + g * 16 + l4 * 4]);
            const int o = wid * 32 + g * 16 + l4 * 4;
            #pragma unroll
            for (int f = 0; f < 2; f++) {
                unsigned short o4[4];
                #pragma unroll
                for (int r = 0; r < 4; r++) {
                    float z = acc[f][g][r] + bv[r];
                    z = z >= 0.f ? z : 0.01f * z;
                    o4[r] = f2h(z);
                }
                const int row = f * 16 + l15;
                *reinterpret_cast<s16x4*>(
                    &R0[row * 256 + (((o >> 3) ^ (row & 7)) << 3) + (o & 7)]) =
                    *reinterpret_cast<const s16x4*>(o4);
            }
        }
    }
    __syncthreads();

    // ---- stage 2: h3 = leaky(h2 @ w2^T + b2).  N=128 (wave owns 16), K=256.
    {
        const unsigned short* Wb = a.w2 + (size_t)kj * 32768 + (size_t)wid * 512 + lane * 8;
        f32x4 acc[2] = {};
        f16x8 bfA, bfB;
        bfA = *reinterpret_cast<const f16x8*>(Wb);
        #pragma unroll
        for (int ss = 0; ss < 4; ss++) {
            const int s0 = ss * 2, s1 = ss * 2 + 1;
            f16x8 af0[2];
            #pragma unroll
            for (int f = 0; f < 2; f++) {
                const int r = f * 16 + l15;
                af0[f] = *reinterpret_cast<const f16x8*>(&R0[r * 256 + (((s0 * 4 + l4) ^ (r & 7)) << 3)]);
            }
            bfB = *reinterpret_cast<const f16x8*>(Wb + (size_t)s1 * 4096);
            #pragma unroll
            for (int f = 0; f < 2; f++)
                MFMA16(bfA, af0[f], acc[f]);
            f16x8 af1[2];
            #pragma unroll
            for (int f = 0; f < 2; f++) {
                const int r = f * 16 + l15;
                af1[f] = *reinterpret_cast<const f16x8*>(&R0[r * 256 + (((s1 * 4 + l4) ^ (r & 7)) << 3)]);
            }
            if (ss < 3) bfA = *reinterpret_cast<const f16x8*>(Wb + (size_t)(s0 + 2) * 4096);
            #pragma unroll
            for (int f = 0; f < 2; f++)
                MFMA16(bfB, af1[f], acc[f]);
        }
        __syncthreads();
        {
            const f32x4 bv = *reinterpret_cast<const f32x4*>(
                &a.bias2[kj * 128 + wid * 16 + l4 * 4]);
            const int o = wid * 16 + l4 * 4;
            #pragma unroll
            for (int f = 0; f < 2; f++) {
                unsigned short o4[4];
                #pragma unroll
                for (int r = 0; r < 4; r++) {
                    float z = acc[f][r] + bv[r];
                    z = z >= 0.f ? z : 0.01f * z;
                    o4[r] = f2h(z);
                }
                const int row = f * 16 + l15;
                *reinterpret_cast<s16x4*>(
                    &R0[row * 128 + (((o >> 3) ^ (row & 7)) << 3) + (o & 7)]) =
                    *reinterpret_cast<const s16x4*>(o4);
            }
        }
    }
    __syncthreads();

    // ---- stage 3: h4 = leaky(h3 @ w3^T + b3).  N=64, K=128. Waves 2M x 4N,
    //      each wave one 16x16 output tile.
    {
        const int wm = wid >> 2, wn4 = wid & 3;
        const unsigned short* Wb = a.w3 + (size_t)kj * 8192 + (size_t)wn4 * 512 + lane * 8;
        f32x4 acc = {};
        #pragma unroll
        for (int s = 0; s < 4; s++) {
            const int r = wm * 16 + l15;
            f16x8 af = *reinterpret_cast<const f16x8*>(&R0[r * 128 + (((s * 4 + l4) ^ (r & 7)) << 3)]);
            f16x8 bf = *reinterpret_cast<const f16x8*>(Wb + (size_t)s * 2048);
            MFMA16(bf, af, acc);
        }
        __syncthreads();
        {
            const f32x4 bv = *reinterpret_cast<const f32x4*>(
                &a.bias3[kj * 64 + wn4 * 16 + l4 * 4]);
            const int o = wn4 * 16 + l4 * 4;
            unsigned short o4[4];
            #pragma unroll
            for (int r = 0; r < 4; r++) {
                float z = acc[r] + bv[r];
                z = z >= 0.f ? z : 0.01f * z;
                o4[r] = f2h(z);
            }
            const int row = wm * 16 + l15;
            *reinterpret_cast<s16x4*>(
                &R0[row * 64 + (((o >> 3) ^ (row & 7)) << 3) + (o & 7)]) =
                *reinterpret_cast<const s16x4*>(o4);
        }
    }
    __syncthreads();

    // ---- stage 4: out = h4 @ w4^T + b4 (f32). 192 threads: one (row,o) each.
    if (tid < 192) {
        const int row = tid / 6, o = tid - row * 6;
        float xv[64];
        #pragma unroll
        for (int ch = 0; ch < 8; ch++) {
            s16x8 v = *reinterpret_cast<const s16x8*>(&R0[row * 64 + ((ch ^ (row & 7)) << 3)]);
            #pragma unroll
            for (int e = 0; e < 8; e++) xv[ch * 8 + e] = h2f((unsigned short)v[e]);
        }
        const float* w4b = a.w4 + kj * 384 + o * 64;
        float sum = a.bias4[kj * 6 + o];
        #pragma unroll
        for (int i = 0; i < 64; i++) sum = fmaf(xv[i], w4b[i], sum);
        __builtin_nontemporal_store(sum, &a.out[((size_t)(m0 + row) * 80 + kj) * 6 + o]);
    }
}

// ---------------------------------------------------------------------------
extern "C" void kernel_launch(void* const* d_in, const int* in_sizes, int n_in,
                              void* d_out, int out_size, void* d_ws, size_t ws_size,
                              hipStream_t stream)
{
    (void)in_sizes; (void)n_in; (void)out_size; (void)ws_size;
    PrepArgs a;
    a.adj  = (const float*)d_in[2];
    a.v0 = (const float*)d_in[4];  a.g0 = (const float*)d_in[5];  a.b0 = (const float*)d_in[6];
    a.v1 = (const float*)d_in[7];  a.g1 = (const float*)d_in[8];  a.b1 = (const float*)d_in[9];
    a.v2 = (const float*)d_in[10]; a.g2 = (const float*)d_in[11]; a.b2 = (const float*)d_in[12];
    a.v3 = (const float*)d_in[13]; a.g3 = (const float*)d_in[14]; a.b3 = (const float*)d_in[15];
    a.v4 = (const float*)d_in[16]; a.g4 = (const float*)d_in[17]; a.b4 = (const float*)d_in[18];

    char* ws = (char*)d_ws;
    size_t off = 0;
    auto alloc = [&](size_t n) -> void* {
        off = (off + 255) & ~(size_t)255;
        void* p = ws + off;
        off += n;
        return p;
    };
    a.w0 = (unsigned short*)alloc(80ull * 512 * 512 * 2);
    a.w1 = (unsigned short*)alloc(80ull * 256 * 512 * 2);
    a.w2 = (unsigned short*)alloc(80ull * 128 * 256 * 2);
    a.w3 = (unsigned short*)alloc(80ull * 64 * 128 * 2);
    a.w4 = (float*)alloc(80ull * 6 * 64 * 4);
    a.bias0 = (float*)alloc(80ull * 512 * 4);
    a.bias1 = (float*)alloc(80ull * 256 * 4);
    a.bias2 = (float*)alloc(80ull * 128 * 4);
    a.bias3 = (float*)alloc(80ull * 64 * 4);
    a.bias4 = (float*)alloc(80ull * 6 * 4);

    MegaArgs m;
    m.qp   = (const float*)d_in[0];
    m.pf   = (const float*)d_in[1];
    m.Brff = (const float*)d_in[3];
    m.w0 = a.w0; m.w1 = a.w1; m.w2 = a.w2; m.w3 = a.w3; m.w4 = a.w4;
    m.bias0 = a.bias0; m.bias1 = a.bias1; m.bias2 = a.bias2;
    m.bias3 = a.bias3; m.bias4 = a.bias4;
    m.out = (float*)d_out;

    (void)hipFuncSetAttribute((const void*)mega9_kernel,
                              hipFuncAttributeMaxDynamicSharedMemorySize, 32768);

    prep_kernel<<<19320, 256, 0, stream>>>(a);
    mega9_kernel<<<5120, 512, 32768, stream>>>(m);
}

// Round 18
// 297.126 us; speedup vs baseline: 1.3467x; 1.3467x over previous
//
#include <hip/hip_runtime.h>
#include <hip/hip_fp16.h>

#define DI __device__ __forceinline__

typedef __attribute__((ext_vector_type(4))) float f32x4;
typedef __attribute__((ext_vector_type(8))) _Float16 f16x8;
typedef __attribute__((ext_vector_type(8))) short s16x8;
typedef __attribute__((ext_vector_type(4))) short s16x4;

DI unsigned short f2h(float f) { return __half_as_ushort(__float2half(f)); }
DI float h2f(unsigned short u) { return __half2float(__ushort_as_half(u)); }

// operand-swapped: A-operand = weight fragment, B-operand = activation fragment.
// D: lane holds o = l4*4+r (4 consecutive channels), batch-row = l15.
#define MFMA16(A, B, C) (C) = __builtin_amdgcn_mfma_f32_16x16x32_f16((A), (B), (C), 0, 0, 0)

// ---------------------------------------------------------------------------
// Prep: weight-norm fold + diag-scale fold, emitting MFMA-FRAGMENT layout:
//   W'[kj][s][n16][lane(l4*16+l15)][8]; a wave's W-frag load = contiguous 1KB.
// ---------------------------------------------------------------------------
struct PrepArgs {
    const float *adj;
    const float *v0,*g0,*b0,*v1,*g1,*b1,*v2,*g2,*b2,*v3,*g3,*b3,*v4,*g4,*b4;
    unsigned short *w0,*w1,*w2,*w3;
    float *w4, *bias0,*bias1,*bias2,*bias3,*bias4;
};

template <int CIN, int CINPAD>
DI void prep_row(const float* __restrict__ v, const float* __restrict__ g,
                 const float* __restrict__ b, const float* __restrict__ adj,
                 int cout, int use_scale,
                 unsigned short* __restrict__ wout, float* __restrict__ biasout,
                 int ridx, int lane)
{
    const int k = ridx / cout;
    const int o = ridx - k * cout;
    const float* vr = v + (size_t)ridx * CIN;
    float xv[8];
    if (lane * 8 < CIN) {
        const f32x4 p0 = *reinterpret_cast<const f32x4*>(&vr[lane * 8]);
        const f32x4 p1 = *reinterpret_cast<const f32x4*>(&vr[lane * 8 + 4]);
        #pragma unroll
        for (int e = 0; e < 4; e++) { xv[e] = p0[e]; xv[4 + e] = p1[e]; }
    } else {
        #pragma unroll
        for (int e = 0; e < 8; e++) xv[e] = 0.f;
    }
    float ss = 0.f;
    #pragma unroll
    for (int e = 0; e < 8; e++) ss += xv[e] * xv[e];
    #pragma unroll
    for (int off = 32; off >= 1; off >>= 1) ss += __shfl_xor(ss, off, 64);
    float s = g[ridx] / sqrtf(ss);
    float bias = b[ridx];
    if (use_scale) {
        float d = adj[k * 81];            // adj[k][k]
        d = d > 0.f ? d : 0.f;
        s *= d; bias *= d;                // leaky(z)*s == leaky(z*s), s>=0
    }
    if (lane == 0) biasout[ridx] = bias;
    if (lane < CINPAD / 8) {
        unsigned short tmp[8];
        #pragma unroll
        for (int e = 0; e < 8; e++) tmp[e] = f2h(xv[e] * s);
        unsigned short* wj = wout + (size_t)k * cout * CINPAD;
        const int sblk = lane >> 2, l4w = lane & 3;
        const size_t pos = (((size_t)sblk * (cout >> 4) + (o >> 4)) * 64 + l4w * 16 + (o & 15)) * 8;
        *reinterpret_cast<s16x8*>(&wj[pos]) = *reinterpret_cast<const s16x8*>(tmp);
    }
}

DI void prep_w4_row(const float* __restrict__ v, const float* __restrict__ g,
                    const float* __restrict__ b, float* __restrict__ wout,
                    float* __restrict__ biasout, int ridx, int lane)
{
    const float x = v[(size_t)ridx * 64 + lane];
    float ss = x * x;
    #pragma unroll
    for (int off = 32; off >= 1; off >>= 1) ss += __shfl_xor(ss, off, 64);
    const float s = g[ridx] / sqrtf(ss);
    if (lane == 0) biasout[ridx] = b[ridx];
    wout[(size_t)ridx * 64 + lane] = x * s;
}

__global__ __launch_bounds__(256) void prep_kernel(PrepArgs a)
{
    const int bid = blockIdx.x, wave = threadIdx.x >> 6, lane = threadIdx.x & 63;
    if (bid < 10240)      prep_row<480, 512>(a.v0, a.g0, a.b0, a.adj, 512, 1, a.w0, a.bias0, bid * 4 + wave, lane);
    else if (bid < 15360) prep_row<512, 512>(a.v1, a.g1, a.b1, a.adj, 256, 1, a.w1, a.bias1, (bid - 10240) * 4 + wave, lane);
    else if (bid < 17920) prep_row<256, 256>(a.v2, a.g2, a.b2, a.adj, 128, 1, a.w2, a.bias2, (bid - 15360) * 4 + wave, lane);
    else if (bid < 19200) prep_row<128, 128>(a.v3, a.g3, a.b3, a.adj,  64, 0, a.w3, a.bias3, (bid - 17920) * 4 + wave, lane);
    else                  prep_w4_row(a.v4, a.g4, a.b4, a.w4, a.bias4, (bid - 19200) * 4 + wave, lane);
}

// ---------------------------------------------------------------------------
// Mega v10 = mega8 (M=64, operand-swapped, fragment-W, XOR swizzle) with
// DEPTH-3 W prefetch in stages 0/1/2. Stage 0 split into two N-passes so the
// hot accumulator halves, freeing VGPRs for the 3-deep rotating W buffer
// (statically indexed s%3 in a fully unrolled loop).
// ---------------------------------------------------------------------------
struct MegaArgs {
    const float *qp, *pf, *Brff;
    const unsigned short *w0, *w1, *w2, *w3;
    const float *w4, *bias0, *bias1, *bias2, *bias3, *bias4;
    float* out;
};

__global__ __launch_bounds__(512, 4) void mega10_kernel(MegaArgs a)
{
    extern __shared__ __align__(16) unsigned short R0[];   // 32768 shorts = 64 KB
    const int tid = threadIdx.x, wid = tid >> 6, lane = tid & 63;
    const int l15 = lane & 15, l4 = lane >> 4;
    const int bid = blockIdx.x;
    const int swz = (bid & 7) * 320 + (bid >> 3);   // XCD-chunked, bijective (2560%8==0)
    const int kj = swz >> 5;
    const int m0 = (swz & 31) * 64;

    // ---- prologue: h0 = pf + RFF(qp)  -> R0 as [64][512] (480 real + 32 zero-pad)
    {
        const int row = tid >> 3;                 // 0..63
        const int tq  = tid & 7;
        const int gr  = (m0 + row) * 80 + kj;     // batch-major global row
        const float q0 = a.qp[gr * 3 + 0], q1 = a.qp[gr * 3 + 1], q2 = a.qp[gr * 3 + 2];
        #pragma unroll
        for (int i = 0; i < 8; i++) {
            const int c0 = tq * 8 + i * 64;       // multiples of 8, 0..504
            unsigned short o[8];
            if (c0 < 480) {
                const bool issin = (c0 >= 240);
                const int j0 = issin ? (c0 - 240) : c0;
                const f32x4 b0a = *reinterpret_cast<const f32x4*>(&a.Brff[j0]);
                const f32x4 b0b = *reinterpret_cast<const f32x4*>(&a.Brff[j0 + 4]);
                const f32x4 b1a = *reinterpret_cast<const f32x4*>(&a.Brff[240 + j0]);
                const f32x4 b1b = *reinterpret_cast<const f32x4*>(&a.Brff[240 + j0 + 4]);
                const f32x4 b2a = *reinterpret_cast<const f32x4*>(&a.Brff[480 + j0]);
                const f32x4 b2b = *reinterpret_cast<const f32x4*>(&a.Brff[480 + j0 + 4]);
                const f32x4 p0 = __builtin_nontemporal_load(
                    reinterpret_cast<const f32x4*>(&a.pf[(size_t)gr * 480 + c0]));
                const f32x4 p1 = __builtin_nontemporal_load(
                    reinterpret_cast<const f32x4*>(&a.pf[(size_t)gr * 480 + c0 + 4]));
                #pragma unroll
                for (int e = 0; e < 4; e++) {
                    float rev = q0 * b0a[e] + q1 * b1a[e] + q2 * b2a[e];
                    rev -= floorf(rev);           // v_sin/v_cos take revolutions
                    float t = issin ? __builtin_amdgcn_sinf(rev) : __builtin_amdgcn_cosf(rev);
                    o[e] = f2h(p0[e] + t);
                }
                #pragma unroll
                for (int e = 0; e < 4; e++) {
                    float rev = q0 * b0b[e] + q1 * b1b[e] + q2 * b2b[e];
                    rev -= floorf(rev);
                    float t = issin ? __builtin_amdgcn_sinf(rev) : __builtin_amdgcn_cosf(rev);
                    o[4 + e] = f2h(p1[e] + t);
                }
            } else {
                #pragma unroll
                for (int e = 0; e < 8; e++) o[e] = 0;
            }
            const int ck = c0 >> 3;
            *reinterpret_cast<s16x8*>(&R0[row * 512 + ((ck ^ (row & 7)) << 3)]) =
                *reinterpret_cast<const s16x8*>(o);
        }
    }
    __syncthreads();

    // ---- stage 0: h1 = leaky(h0 @ w0^T + b0).  N=512 (wave owns 64 cols), K=512.
    //      Two N-passes (g-pairs), depth-3 rotating W prefetch per pass.
    {
        const unsigned short* Wb = a.w0 + (size_t)kj * 262144 + (size_t)(wid * 4) * 512 + lane * 8;
        f32x4 acc[4][4] = {};
        #pragma unroll
        for (int pass = 0; pass < 2; pass++) {
            const unsigned short* Wp = Wb + pass * 2 * 512;
            f16x8 buf[3][2];
            #pragma unroll
            for (int d = 0; d < 3; d++)
                #pragma unroll
                for (int gg = 0; gg < 2; gg++)
                    buf[d][gg] = *reinterpret_cast<const f16x8*>(Wp + (size_t)d * 16384 + gg * 512);
            #pragma unroll
            for (int s = 0; s < 16; s++) {
                f16x8 af[4];
                #pragma unroll
                for (int f = 0; f < 4; f++) {
                    const int r = f * 16 + l15;
                    af[f] = *reinterpret_cast<const f16x8*>(&R0[r * 512 + (((s * 4 + l4) ^ (r & 7)) << 3)]);
                }
                #pragma unroll
                for (int f = 0; f < 4; f++)
                    #pragma unroll
                    for (int gg = 0; gg < 2; gg++)
                        MFMA16(buf[s % 3][gg], af[f], acc[f][pass * 2 + gg]);
                if (s + 3 < 16) {
                    #pragma unroll
                    for (int gg = 0; gg < 2; gg++)
                        buf[s % 3][gg] = *reinterpret_cast<const f16x8*>(Wp + (size_t)(s + 3) * 16384 + gg * 512);
                }
            }
        }
        __syncthreads();                          // all h0 reads done
        #pragma unroll
        for (int g = 0; g < 4; g++) {
            const f32x4 bv = *reinterpret_cast<const f32x4*>(
                &a.bias0[kj * 512 + wid * 64 + g * 16 + l4 * 4]);
            const int o = wid * 64 + g * 16 + l4 * 4;
            #pragma unroll
            for (int f = 0; f < 4; f++) {
                unsigned short o4[4];
                #pragma unroll
                for (int r = 0; r < 4; r++) {
                    float z = acc[f][g][r] + bv[r];
                    z = z >= 0.f ? z : 0.01f * z;
                    o4[r] = f2h(z);
                }
                const int row = f * 16 + l15;
                *reinterpret_cast<s16x4*>(
                    &R0[row * 512 + (((o >> 3) ^ (row & 7)) << 3) + (o & 7)]) =
                    *reinterpret_cast<const s16x4*>(o4);
            }
        }
    }
    __syncthreads();

    // ---- stage 1: h2 = leaky(h1 @ w1^T + b1).  N=256 (wave owns 32), K=512.
    //      Depth-3 rotating W prefetch.
    {
        const unsigned short* Wb = a.w1 + (size_t)kj * 131072 + (size_t)(wid * 2) * 512 + lane * 8;
        f32x4 acc[4][2] = {};
        f16x8 buf[3][2];
        #pragma unroll
        for (int d = 0; d < 3; d++)
            #pragma unroll
            for (int g = 0; g < 2; g++)
                buf[d][g] = *reinterpret_cast<const f16x8*>(Wb + (size_t)d * 8192 + g * 512);
        #pragma unroll
        for (int s = 0; s < 16; s++) {
            f16x8 af[4];
            #pragma unroll
            for (int f = 0; f < 4; f++) {
                const int r = f * 16 + l15;
                af[f] = *reinterpret_cast<const f16x8*>(&R0[r * 512 + (((s * 4 + l4) ^ (r & 7)) << 3)]);
            }
            #pragma unroll
            for (int f = 0; f < 4; f++)
                #pragma unroll
                for (int g = 0; g < 2; g++)
                    MFMA16(buf[s % 3][g], af[f], acc[f][g]);
            if (s + 3 < 16) {
                #pragma unroll
                for (int g = 0; g < 2; g++)
                    buf[s % 3][g] = *reinterpret_cast<const f16x8*>(Wb + (size_t)(s + 3) * 8192 + g * 512);
            }
        }
        __syncthreads();
        #pragma unroll
        for (int g = 0; g < 2; g++) {
            const f32x4 bv = *reinterpret_cast<const f32x4*>(
                &a.bias1[kj * 256 + wid * 32 + g * 16 + l4 * 4]);
            const int o = wid * 32 + g * 16 + l4 * 4;
            #pragma unroll
            for (int f = 0; f < 4; f++) {
                unsigned short o4[4];
                #pragma unroll
                for (int r = 0; r < 4; r++) {
                    float z = acc[f][g][r] + bv[r];
                    z = z >= 0.f ? z : 0.01f * z;
                    o4[r] = f2h(z);
                }
                const int row = f * 16 + l15;
                *reinterpret_cast<s16x4*>(
                    &R0[row * 256 + (((o >> 3) ^ (row & 7)) << 3) + (o & 7)]) =
                    *reinterpret_cast<const s16x4*>(o4);
            }
        }
    }
    __syncthreads();

    // ---- stage 2: h3 = leaky(h2 @ w2^T + b2).  N=128 (wave owns 16), K=256.
    //      Depth-3 rotating W prefetch.
    {
        const unsigned short* Wb = a.w2 + (size_t)kj * 32768 + (size_t)wid * 512 + lane * 8;
        f32x4 acc[4] = {};
        f16x8 buf[3];
        #pragma unroll
        for (int d = 0; d < 3; d++)
            buf[d] = *reinterpret_cast<const f16x8*>(Wb + (size_t)d * 4096);
        #pragma unroll
        for (int s = 0; s < 8; s++) {
            f16x8 af[4];
            #pragma unroll
            for (int f = 0; f < 4; f++) {
                const int r = f * 16 + l15;
                af[f] = *reinterpret_cast<const f16x8*>(&R0[r * 256 + (((s * 4 + l4) ^ (r & 7)) << 3)]);
            }
            #pragma unroll
            for (int f = 0; f < 4; f++)
                MFMA16(buf[s % 3], af[f], acc[f]);
            if (s + 3 < 8)
                buf[s % 3] = *reinterpret_cast<const f16x8*>(Wb + (size_t)(s + 3) * 4096);
        }
        __syncthreads();
        {
            const f32x4 bv = *reinterpret_cast<const f32x4*>(
                &a.bias2[kj * 128 + wid * 16 + l4 * 4]);
            const int o = wid * 16 + l4 * 4;
            #pragma unroll
            for (int f = 0; f < 4; f++) {
                unsigned short o4[4];
                #pragma unroll
                for (int r = 0; r < 4; r++) {
                    float z = acc[f][r] + bv[r];
                    z = z >= 0.f ? z : 0.01f * z;
                    o4[r] = f2h(z);
                }
                const int row = f * 16 + l15;
                *reinterpret_cast<s16x4*>(
                    &R0[row * 128 + (((o >> 3) ^ (row & 7)) << 3) + (o & 7)]) =
                    *reinterpret_cast<const s16x4*>(o4);
            }
        }
    }
    __syncthreads();

    // ---- stage 3: h4 = leaky(h3 @ w3^T + b3).  N=64, K=128. Waves 2M x 4N.
    {
        const int wm = wid >> 2, wn4 = wid & 3;
        const unsigned short* Wb = a.w3 + (size_t)kj * 8192 + (size_t)wn4 * 512 + lane * 8;
        f32x4 acc[2] = {};
        #pragma unroll
        for (int s = 0; s < 4; s++) {
            f16x8 af[2], bf;
            #pragma unroll
            for (int f = 0; f < 2; f++) {
                const int r = wm * 32 + f * 16 + l15;
                af[f] = *reinterpret_cast<const f16x8*>(&R0[r * 128 + (((s * 4 + l4) ^ (r & 7)) << 3)]);
            }
            bf = *reinterpret_cast<const f16x8*>(Wb + (size_t)s * 2048);
            #pragma unroll
            for (int f = 0; f < 2; f++)
                MFMA16(bf, af[f], acc[f]);
        }
        __syncthreads();
        {
            const f32x4 bv = *reinterpret_cast<const f32x4*>(
                &a.bias3[kj * 64 + wn4 * 16 + l4 * 4]);
            const int o = wn4 * 16 + l4 * 4;
            #pragma unroll
            for (int f = 0; f < 2; f++) {
                unsigned short o4[4];
                #pragma unroll
                for (int r = 0; r < 4; r++) {
                    float z = acc[f][r] + bv[r];
                    z = z >= 0.f ? z : 0.01f * z;
                    o4[r] = f2h(z);
                }
                const int row = wm * 32 + f * 16 + l15;
                *reinterpret_cast<s16x4*>(
                    &R0[row * 64 + (((o >> 3) ^ (row & 7)) << 3) + (o & 7)]) =
                    *reinterpret_cast<const s16x4*>(o4);
            }
        }
    }
    __syncthreads();

    // ---- stage 4: out = h4 @ w4^T + b4 (f32, 6 outputs per row, NT stores).
    if (tid < 64) {
        const int row = tid;
        float xv[64];
        #pragma unroll
        for (int ch = 0; ch < 8; ch++) {
            s16x8 v = *reinterpret_cast<const s16x8*>(&R0[row * 64 + ((ch ^ (row & 7)) << 3)]);
            #pragma unroll
            for (int e = 0; e < 8; e++) xv[ch * 8 + e] = h2f((unsigned short)v[e]);
        }
        const float* w4b = a.w4 + kj * 384;
        float* op = a.out + ((size_t)(m0 + row) * 80 + kj) * 6;
        #pragma unroll
        for (int o = 0; o < 6; o++) {
            float sum = a.bias4[kj * 6 + o];
            #pragma unroll
            for (int i = 0; i < 64; i++) sum = fmaf(xv[i], w4b[o * 64 + i], sum);
            __builtin_nontemporal_store(sum, &op[o]);
        }
    }
}

// ---------------------------------------------------------------------------
extern "C" void kernel_launch(void* const* d_in, const int* in_sizes, int n_in,
                              void* d_out, int out_size, void* d_ws, size_t ws_size,
                              hipStream_t stream)
{
    (void)in_sizes; (void)n_in; (void)out_size; (void)ws_size;
    PrepArgs a;
    a.adj  = (const float*)d_in[2];
    a.v0 = (const float*)d_in[4];  a.g0 = (const float*)d_in[5];  a.b0 = (const float*)d_in[6];
    a.v1 = (const float*)d_in[7];  a.g1 = (const float*)d_in[8];  a.b1 = (const float*)d_in[9];
    a.v2 = (const float*)d_in[10]; a.g2 = (const float*)d_in[11]; a.b2 = (const float*)d_in[12];
    a.v3 = (const float*)d_in[13]; a.g3 = (const float*)d_in[14]; a.b3 = (const float*)d_in[15];
    a.v4 = (const float*)d_in[16]; a.g4 = (const float*)d_in[17]; a.b4 = (const float*)d_in[18];

    char* ws = (char*)d_ws;
    size_t off = 0;
    auto alloc = [&](size_t n) -> void* {
        off = (off + 255) & ~(size_t)255;
        void* p = ws + off;
        off += n;
        return p;
    };
    a.w0 = (unsigned short*)alloc(80ull * 512 * 512 * 2);
    a.w1 = (unsigned short*)alloc(80ull * 256 * 512 * 2);
    a.w2 = (unsigned short*)alloc(80ull * 128 * 256 * 2);
    a.w3 = (unsigned short*)alloc(80ull * 64 * 128 * 2);
    a.w4 = (float*)alloc(80ull * 6 * 64 * 4);
    a.bias0 = (float*)alloc(80ull * 512 * 4);
    a.bias1 = (float*)alloc(80ull * 256 * 4);
    a.bias2 = (float*)alloc(80ull * 128 * 4);
    a.bias3 = (float*)alloc(80ull * 64 * 4);
    a.bias4 = (float*)alloc(80ull * 6 * 4);

    MegaArgs m;
    m.qp   = (const float*)d_in[0];
    m.pf   = (const float*)d_in[1];
    m.Brff = (const float*)d_in[3];
    m.w0 = a.w0; m.w1 = a.w1; m.w2 = a.w2; m.w3 = a.w3; m.w4 = a.w4;
    m.bias0 = a.bias0; m.bias1 = a.bias1; m.bias2 = a.bias2;
    m.bias3 = a.bias3; m.bias4 = a.bias4;
    m.out = (float*)d_out;

    (void)hipFuncSetAttribute((const void*)mega10_kernel,
                              hipFuncAttributeMaxDynamicSharedMemorySize, 65536);

    prep_kernel<<<19320, 256, 0, stream>>>(a);
    mega10_kernel<<<2560, 512, 65536, stream>>>(m);
}

// Round 19
// 296.106 us; speedup vs baseline: 1.3513x; 1.0034x over previous
//
#include <hip/hip_runtime.h>
#include <hip/hip_fp16.h>

#define DI __device__ __forceinline__

typedef __attribute__((ext_vector_type(4))) float f32x4;
typedef __attribute__((ext_vector_type(8))) _Float16 f16x8;
typedef __attribute__((ext_vector_type(8))) short s16x8;
typedef __attribute__((ext_vector_type(4))) short s16x4;

DI unsigned short f2h(float f) { return __half_as_ushort(__float2half(f)); }
DI float h2f(unsigned short u) { return __half2float(__ushort_as_half(u)); }

// operand-swapped: A-operand = weight fragment, B-operand = activation fragment.
// D: lane holds o = l4*4+r (4 consecutive channels), batch-row = l15.
#define MFMA16(A, B, C) (C) = __builtin_amdgcn_mfma_f32_16x16x32_f16((A), (B), (C), 0, 0, 0)
#define PRIO1 __builtin_amdgcn_s_setprio(1)
#define PRIO0 __builtin_amdgcn_s_setprio(0)

// ---------------------------------------------------------------------------
// Prep: weight-norm fold + diag-scale fold, emitting MFMA-FRAGMENT layout:
//   W'[kj][s][n16][lane(l4*16+l15)][8]; a wave's W-frag load = contiguous 1KB.
// ---------------------------------------------------------------------------
struct PrepArgs {
    const float *adj;
    const float *v0,*g0,*b0,*v1,*g1,*b1,*v2,*g2,*b2,*v3,*g3,*b3,*v4,*g4,*b4;
    unsigned short *w0,*w1,*w2,*w3;
    float *w4, *bias0,*bias1,*bias2,*bias3,*bias4;
};

template <int CIN, int CINPAD>
DI void prep_row(const float* __restrict__ v, const float* __restrict__ g,
                 const float* __restrict__ b, const float* __restrict__ adj,
                 int cout, int use_scale,
                 unsigned short* __restrict__ wout, float* __restrict__ biasout,
                 int ridx, int lane)
{
    const int k = ridx / cout;
    const int o = ridx - k * cout;
    const float* vr = v + (size_t)ridx * CIN;
    float xv[8];
    if (lane * 8 < CIN) {
        const f32x4 p0 = *reinterpret_cast<const f32x4*>(&vr[lane * 8]);
        const f32x4 p1 = *reinterpret_cast<const f32x4*>(&vr[lane * 8 + 4]);
        #pragma unroll
        for (int e = 0; e < 4; e++) { xv[e] = p0[e]; xv[4 + e] = p1[e]; }
    } else {
        #pragma unroll
        for (int e = 0; e < 8; e++) xv[e] = 0.f;
    }
    float ss = 0.f;
    #pragma unroll
    for (int e = 0; e < 8; e++) ss += xv[e] * xv[e];
    #pragma unroll
    for (int off = 32; off >= 1; off >>= 1) ss += __shfl_xor(ss, off, 64);
    float s = g[ridx] / sqrtf(ss);
    float bias = b[ridx];
    if (use_scale) {
        float d = adj[k * 81];            // adj[k][k]
        d = d > 0.f ? d : 0.f;
        s *= d; bias *= d;                // leaky(z)*s == leaky(z*s), s>=0
    }
    if (lane == 0) biasout[ridx] = bias;
    if (lane < CINPAD / 8) {
        unsigned short tmp[8];
        #pragma unroll
        for (int e = 0; e < 8; e++) tmp[e] = f2h(xv[e] * s);
        unsigned short* wj = wout + (size_t)k * cout * CINPAD;
        const int sblk = lane >> 2, l4w = lane & 3;
        const size_t pos = (((size_t)sblk * (cout >> 4) + (o >> 4)) * 64 + l4w * 16 + (o & 15)) * 8;
        *reinterpret_cast<s16x8*>(&wj[pos]) = *reinterpret_cast<const s16x8*>(tmp);
    }
}

DI void prep_w4_row(const float* __restrict__ v, const float* __restrict__ g,
                    const float* __restrict__ b, float* __restrict__ wout,
                    float* __restrict__ biasout, int ridx, int lane)
{
    const float x = v[(size_t)ridx * 64 + lane];
    float ss = x * x;
    #pragma unroll
    for (int off = 32; off >= 1; off >>= 1) ss += __shfl_xor(ss, off, 64);
    const float s = g[ridx] / sqrtf(ss);
    if (lane == 0) biasout[ridx] = b[ridx];
    wout[(size_t)ridx * 64 + lane] = x * s;
}

__global__ __launch_bounds__(256) void prep_kernel(PrepArgs a)
{
    const int bid = blockIdx.x, wave = threadIdx.x >> 6, lane = threadIdx.x & 63;
    if (bid < 10240)      prep_row<480, 512>(a.v0, a.g0, a.b0, a.adj, 512, 1, a.w0, a.bias0, bid * 4 + wave, lane);
    else if (bid < 15360) prep_row<512, 512>(a.v1, a.g1, a.b1, a.adj, 256, 1, a.w1, a.bias1, (bid - 10240) * 4 + wave, lane);
    else if (bid < 17920) prep_row<256, 256>(a.v2, a.g2, a.b2, a.adj, 128, 1, a.w2, a.bias2, (bid - 15360) * 4 + wave, lane);
    else if (bid < 19200) prep_row<128, 128>(a.v3, a.g3, a.b3, a.adj,  64, 0, a.w3, a.bias3, (bid - 17920) * 4 + wave, lane);
    else                  prep_w4_row(a.v4, a.g4, a.b4, a.w4, a.bias4, (bid - 19200) * 4 + wave, lane);
}

// ---------------------------------------------------------------------------
// Mega v11 = mega8 byte-identical + s_setprio(1) around MFMA clusters only.
// (2 independent blocks/CU give wave role diversity -> T5's paying regime.)
// ---------------------------------------------------------------------------
struct MegaArgs {
    const float *qp, *pf, *Brff;
    const unsigned short *w0, *w1, *w2, *w3;
    const float *w4, *bias0, *bias1, *bias2, *bias3, *bias4;
    float* out;
};

__global__ __launch_bounds__(512, 4) void mega11_kernel(MegaArgs a)
{
    extern __shared__ __align__(16) unsigned short R0[];   // 32768 shorts = 64 KB
    const int tid = threadIdx.x, wid = tid >> 6, lane = tid & 63;
    const int l15 = lane & 15, l4 = lane >> 4;
    const int bid = blockIdx.x;
    const int swz = (bid & 7) * 320 + (bid >> 3);   // XCD-chunked, bijective (2560%8==0)
    const int kj = swz >> 5;
    const int m0 = (swz & 31) * 64;

    // ---- prologue: h0 = pf + RFF(qp)  -> R0 as [64][512] (480 real + 32 zero-pad)
    {
        const int row = tid >> 3;                 // 0..63
        const int tq  = tid & 7;
        const int gr  = (m0 + row) * 80 + kj;     // batch-major global row
        const float q0 = a.qp[gr * 3 + 0], q1 = a.qp[gr * 3 + 1], q2 = a.qp[gr * 3 + 2];
        #pragma unroll
        for (int i = 0; i < 8; i++) {
            const int c0 = tq * 8 + i * 64;       // multiples of 8, 0..504
            unsigned short o[8];
            if (c0 < 480) {
                const bool issin = (c0 >= 240);
                const int j0 = issin ? (c0 - 240) : c0;
                const f32x4 b0a = *reinterpret_cast<const f32x4*>(&a.Brff[j0]);
                const f32x4 b0b = *reinterpret_cast<const f32x4*>(&a.Brff[j0 + 4]);
                const f32x4 b1a = *reinterpret_cast<const f32x4*>(&a.Brff[240 + j0]);
                const f32x4 b1b = *reinterpret_cast<const f32x4*>(&a.Brff[240 + j0 + 4]);
                const f32x4 b2a = *reinterpret_cast<const f32x4*>(&a.Brff[480 + j0]);
                const f32x4 b2b = *reinterpret_cast<const f32x4*>(&a.Brff[480 + j0 + 4]);
                const f32x4 p0 = __builtin_nontemporal_load(
                    reinterpret_cast<const f32x4*>(&a.pf[(size_t)gr * 480 + c0]));
                const f32x4 p1 = __builtin_nontemporal_load(
                    reinterpret_cast<const f32x4*>(&a.pf[(size_t)gr * 480 + c0 + 4]));
                #pragma unroll
                for (int e = 0; e < 4; e++) {
                    float rev = q0 * b0a[e] + q1 * b1a[e] + q2 * b2a[e];
                    rev -= floorf(rev);           // v_sin/v_cos take revolutions
                    float t = issin ? __builtin_amdgcn_sinf(rev) : __builtin_amdgcn_cosf(rev);
                    o[e] = f2h(p0[e] + t);
                }
                #pragma unroll
                for (int e = 0; e < 4; e++) {
                    float rev = q0 * b0b[e] + q1 * b1b[e] + q2 * b2b[e];
                    rev -= floorf(rev);
                    float t = issin ? __builtin_amdgcn_sinf(rev) : __builtin_amdgcn_cosf(rev);
                    o[4 + e] = f2h(p1[e] + t);
                }
            } else {
                #pragma unroll
                for (int e = 0; e < 8; e++) o[e] = 0;
            }
            const int ck = c0 >> 3;
            *reinterpret_cast<s16x8*>(&R0[row * 512 + ((ck ^ (row & 7)) << 3)]) =
                *reinterpret_cast<const s16x8*>(o);
        }
    }
    __syncthreads();

    // ---- stage 0: h1 = leaky(h0 @ w0^T + b0).  N=512 (wave owns 64 cols), K=512.
    {
        const unsigned short* Wb = a.w0 + (size_t)kj * 262144 + (size_t)(wid * 4) * 512 + lane * 8;
        f32x4 acc[4][4] = {};
        f16x8 bfA[4], bfB[4];
        #pragma unroll
        for (int g = 0; g < 4; g++) bfA[g] = *reinterpret_cast<const f16x8*>(Wb + g * 512);
        #pragma unroll
        for (int ss = 0; ss < 8; ss++) {
            const int s0 = ss * 2, s1 = ss * 2 + 1;
            f16x8 af0[4];
            #pragma unroll
            for (int f = 0; f < 4; f++) {
                const int r = f * 16 + l15;
                af0[f] = *reinterpret_cast<const f16x8*>(&R0[r * 512 + (((s0 * 4 + l4) ^ (r & 7)) << 3)]);
            }
            #pragma unroll
            for (int g = 0; g < 4; g++)
                bfB[g] = *reinterpret_cast<const f16x8*>(Wb + (size_t)s1 * 16384 + g * 512);
            PRIO1;
            #pragma unroll
            for (int f = 0; f < 4; f++)
                #pragma unroll
                for (int g = 0; g < 4; g++)
                    MFMA16(bfA[g], af0[f], acc[f][g]);
            PRIO0;
            f16x8 af1[4];
            #pragma unroll
            for (int f = 0; f < 4; f++) {
                const int r = f * 16 + l15;
                af1[f] = *reinterpret_cast<const f16x8*>(&R0[r * 512 + (((s1 * 4 + l4) ^ (r & 7)) << 3)]);
            }
            if (ss < 7) {
                #pragma unroll
                for (int g = 0; g < 4; g++)
                    bfA[g] = *reinterpret_cast<const f16x8*>(Wb + (size_t)(s0 + 2) * 16384 + g * 512);
            }
            PRIO1;
            #pragma unroll
            for (int f = 0; f < 4; f++)
                #pragma unroll
                for (int g = 0; g < 4; g++)
                    MFMA16(bfB[g], af1[f], acc[f][g]);
            PRIO0;
        }
        __syncthreads();                          // all h0 reads done
        #pragma unroll
        for (int g = 0; g < 4; g++) {
            const f32x4 bv = *reinterpret_cast<const f32x4*>(
                &a.bias0[kj * 512 + wid * 64 + g * 16 + l4 * 4]);
            const int o = wid * 64 + g * 16 + l4 * 4;
            #pragma unroll
            for (int f = 0; f < 4; f++) {
                unsigned short o4[4];
                #pragma unroll
                for (int r = 0; r < 4; r++) {
                    float z = acc[f][g][r] + bv[r];
                    z = z >= 0.f ? z : 0.01f * z;
                    o4[r] = f2h(z);
                }
                const int row = f * 16 + l15;
                *reinterpret_cast<s16x4*>(
                    &R0[row * 512 + (((o >> 3) ^ (row & 7)) << 3) + (o & 7)]) =
                    *reinterpret_cast<const s16x4*>(o4);
            }
        }
    }
    __syncthreads();

    // ---- stage 1: h2 = leaky(h1 @ w1^T + b1).  N=256 (wave owns 32), K=512.
    {
        const unsigned short* Wb = a.w1 + (size_t)kj * 131072 + (size_t)(wid * 2) * 512 + lane * 8;
        f32x4 acc[4][2] = {};
        f16x8 bfA[2], bfB[2];
        #pragma unroll
        for (int g = 0; g < 2; g++) bfA[g] = *reinterpret_cast<const f16x8*>(Wb + g * 512);
        #pragma unroll
        for (int ss = 0; ss < 8; ss++) {
            const int s0 = ss * 2, s1 = ss * 2 + 1;
            f16x8 af0[4];
            #pragma unroll
            for (int f = 0; f < 4; f++) {
                const int r = f * 16 + l15;
                af0[f] = *reinterpret_cast<const f16x8*>(&R0[r * 512 + (((s0 * 4 + l4) ^ (r & 7)) << 3)]);
            }
            #pragma unroll
            for (int g = 0; g < 2; g++)
                bfB[g] = *reinterpret_cast<const f16x8*>(Wb + (size_t)s1 * 8192 + g * 512);
            PRIO1;
            #pragma unroll
            for (int f = 0; f < 4; f++)
                #pragma unroll
                for (int g = 0; g < 2; g++)
                    MFMA16(bfA[g], af0[f], acc[f][g]);
            PRIO0;
            f16x8 af1[4];
            #pragma unroll
            for (int f = 0; f < 4; f++) {
                const int r = f * 16 + l15;
                af1[f] = *reinterpret_cast<const f16x8*>(&R0[r * 512 + (((s1 * 4 + l4) ^ (r & 7)) << 3)]);
            }
            if (ss < 7) {
                #pragma unroll
                for (int g = 0; g < 2; g++)
                    bfA[g] = *reinterpret_cast<const f16x8*>(Wb + (size_t)(s0 + 2) * 8192 + g * 512);
            }
            PRIO1;
            #pragma unroll
            for (int f = 0; f < 4; f++)
                #pragma unroll
                for (int g = 0; g < 2; g++)
                    MFMA16(bfB[g], af1[f], acc[f][g]);
            PRIO0;
        }
        __syncthreads();
        #pragma unroll
        for (int g = 0; g < 2; g++) {
            const f32x4 bv = *reinterpret_cast<const f32x4*>(
                &a.bias1[kj * 256 + wid * 32 + g * 16 + l4 * 4]);
            const int o = wid * 32 + g * 16 + l4 * 4;
            #pragma unroll
            for (int f = 0; f < 4; f++) {
                unsigned short o4[4];
                #pragma unroll
                for (int r = 0; r < 4; r++) {
                    float z = acc[f][g][r] + bv[r];
                    z = z >= 0.f ? z : 0.01f * z;
                    o4[r] = f2h(z);
                }
                const int row = f * 16 + l15;
                *reinterpret_cast<s16x4*>(
                    &R0[row * 256 + (((o >> 3) ^ (row & 7)) << 3) + (o & 7)]) =
                    *reinterpret_cast<const s16x4*>(o4);
            }
        }
    }
    __syncthreads();

    // ---- stage 2: h3 = leaky(h2 @ w2^T + b2).  N=128 (wave owns 16), K=256.
    {
        const unsigned short* Wb = a.w2 + (size_t)kj * 32768 + (size_t)wid * 512 + lane * 8;
        f32x4 acc[4] = {};
        f16x8 bfA, bfB;
        bfA = *reinterpret_cast<const f16x8*>(Wb);
        #pragma unroll
        for (int ss = 0; ss < 4; ss++) {
            const int s0 = ss * 2, s1 = ss * 2 + 1;
            f16x8 af0[4];
            #pragma unroll
            for (int f = 0; f < 4; f++) {
                const int r = f * 16 + l15;
                af0[f] = *reinterpret_cast<const f16x8*>(&R0[r * 256 + (((s0 * 4 + l4) ^ (r & 7)) << 3)]);
            }
            bfB = *reinterpret_cast<const f16x8*>(Wb + (size_t)s1 * 4096);
            PRIO1;
            #pragma unroll
            for (int f = 0; f < 4; f++)
                MFMA16(bfA, af0[f], acc[f]);
            PRIO0;
            f16x8 af1[4];
            #pragma unroll
            for (int f = 0; f < 4; f++) {
                const int r = f * 16 + l15;
                af1[f] = *reinterpret_cast<const f16x8*>(&R0[r * 256 + (((s1 * 4 + l4) ^ (r & 7)) << 3)]);
            }
            if (ss < 3) bfA = *reinterpret_cast<const f16x8*>(Wb + (size_t)(s0 + 2) * 4096);
            PRIO1;
            #pragma unroll
            for (int f = 0; f < 4; f++)
                MFMA16(bfB, af1[f], acc[f]);
            PRIO0;
        }
        __syncthreads();
        {
            const f32x4 bv = *reinterpret_cast<const f32x4*>(
                &a.bias2[kj * 128 + wid * 16 + l4 * 4]);
            const int o = wid * 16 + l4 * 4;
            #pragma unroll
            for (int f = 0; f < 4; f++) {
                unsigned short o4[4];
                #pragma unroll
                for (int r = 0; r < 4; r++) {
                    float z = acc[f][r] + bv[r];
                    z = z >= 0.f ? z : 0.01f * z;
                    o4[r] = f2h(z);
                }
                const int row = f * 16 + l15;
                *reinterpret_cast<s16x4*>(
                    &R0[row * 128 + (((o >> 3) ^ (row & 7)) << 3) + (o & 7)]) =
                    *reinterpret_cast<const s16x4*>(o4);
            }
        }
    }
    __syncthreads();

    // ---- stage 3: h4 = leaky(h3 @ w3^T + b3).  N=64, K=128. Waves 2M x 4N.
    {
        const int wm = wid >> 2, wn4 = wid & 3;
        const unsigned short* Wb = a.w3 + (size_t)kj * 8192 + (size_t)wn4 * 512 + lane * 8;
        f32x4 acc[2] = {};
        #pragma unroll
        for (int s = 0; s < 4; s++) {
            f16x8 af[2], bf;
            #pragma unroll
            for (int f = 0; f < 2; f++) {
                const int r = wm * 32 + f * 16 + l15;
                af[f] = *reinterpret_cast<const f16x8*>(&R0[r * 128 + (((s * 4 + l4) ^ (r & 7)) << 3)]);
            }
            bf = *reinterpret_cast<const f16x8*>(Wb + (size_t)s * 2048);
            PRIO1;
            #pragma unroll
            for (int f = 0; f < 2; f++)
                MFMA16(bf, af[f], acc[f]);
            PRIO0;
        }
        __syncthreads();
        {
            const f32x4 bv = *reinterpret_cast<const f32x4*>(
                &a.bias3[kj * 64 + wn4 * 16 + l4 * 4]);
            const int o = wn4 * 16 + l4 * 4;
            #pragma unroll
            for (int f = 0; f < 2; f++) {
                unsigned short o4[4];
                #pragma unroll
                for (int r = 0; r < 4; r++) {
                    float z = acc[f][r] + bv[r];
                    z = z >= 0.f ? z : 0.01f * z;
                    o4[r] = f2h(z);
                }
                const int row = wm * 32 + f * 16 + l15;
                *reinterpret_cast<s16x4*>(
                    &R0[row * 64 + (((o >> 3) ^ (row & 7)) << 3) + (o & 7)]) =
                    *reinterpret_cast<const s16x4*>(o4);
            }
        }
    }
    __syncthreads();

    // ---- stage 4: out = h4 @ w4^T + b4 (f32, 6 outputs per row, NT stores).
    if (tid < 64) {
        const int row = tid;
        float xv[64];
        #pragma unroll
        for (int ch = 0; ch < 8; ch++) {
            s16x8 v = *reinterpret_cast<const s16x8*>(&R0[row * 64 + ((ch ^ (row & 7)) << 3)]);
            #pragma unroll
            for (int e = 0; e < 8; e++) xv[ch * 8 + e] = h2f((unsigned short)v[e]);
        }
        const float* w4b = a.w4 + kj * 384;
        float* op = a.out + ((size_t)(m0 + row) * 80 + kj) * 6;
        #pragma unroll
        for (int o = 0; o < 6; o++) {
            float sum = a.bias4[kj * 6 + o];
            #pragma unroll
            for (int i = 0; i < 64; i++) sum = fmaf(xv[i], w4b[o * 64 + i], sum);
            __builtin_nontemporal_store(sum, &op[o]);
        }
    }
}

// ---------------------------------------------------------------------------
extern "C" void kernel_launch(void* const* d_in, const int* in_sizes, int n_in,
                              void* d_out, int out_size, void* d_ws, size_t ws_size,
                              hipStream_t stream)
{
    (void)in_sizes; (void)n_in; (void)out_size; (void)ws_size;
    PrepArgs a;
    a.adj  = (const float*)d_in[2];
    a.v0 = (const float*)d_in[4];  a.g0 = (const float*)d_in[5];  a.b0 = (const float*)d_in[6];
    a.v1 = (const float*)d_in[7];  a.g1 = (const float*)d_in[8];  a.b1 = (const float*)d_in[9];
    a.v2 = (const float*)d_in[10]; a.g2 = (const float*)d_in[11]; a.b2 = (const float*)d_in[12];
    a.v3 = (const float*)d_in[13]; a.g3 = (const float*)d_in[14]; a.b3 = (const float*)d_in[15];
    a.v4 = (const float*)d_in[16]; a.g4 = (const float*)d_in[17]; a.b4 = (const float*)d_in[18];

    char* ws = (char*)d_ws;
    size_t off = 0;
    auto alloc = [&](size_t n) -> void* {
        off = (off + 255) & ~(size_t)255;
        void* p = ws + off;
        off += n;
        return p;
    };
    a.w0 = (unsigned short*)alloc(80ull * 512 * 512 * 2);
    a.w1 = (unsigned short*)alloc(80ull * 256 * 512 * 2);
    a.w2 = (unsigned short*)alloc(80ull * 128 * 256 * 2);
    a.w3 = (unsigned short*)alloc(80ull * 64 * 128 * 2);
    a.w4 = (float*)alloc(80ull * 6 * 64 * 4);
    a.bias0 = (float*)alloc(80ull * 512 * 4);
    a.bias1 = (float*)alloc(80ull * 256 * 4);
    a.bias2 = (float*)alloc(80ull * 128 * 4);
    a.bias3 = (float*)alloc(80ull * 64 * 4);
    a.bias4 = (float*)alloc(80ull * 6 * 4);

    MegaArgs m;
    m.qp   = (const float*)d_in[0];
    m.pf   = (const float*)d_in[1];
    m.Brff = (const float*)d_in[3];
    m.w0 = a.w0; m.w1 = a.w1; m.w2 = a.w2; m.w3 = a.w3; m.w4 = a.w4;
    m.bias0 = a.bias0; m.bias1 = a.bias1; m.bias2 = a.bias2;
    m.bias3 = a.bias3; m.bias4 = a.bias4;
    m.out = (float*)d_out;

    (void)hipFuncSetAttribute((const void*)mega11_kernel,
                              hipFuncAttributeMaxDynamicSharedMemorySize, 65536);

    prep_kernel<<<19320, 256, 0, stream>>>(a);
    mega11_kernel<<<2560, 512, 65536, stream>>>(m);
}

// Round 20
// 278.999 us; speedup vs baseline: 1.4342x; 1.0613x over previous
//
#include <hip/hip_runtime.h>
#include <hip/hip_fp16.h>

#define DI __device__ __forceinline__

typedef __attribute__((ext_vector_type(4))) float f32x4;
typedef __attribute__((ext_vector_type(8))) _Float16 f16x8;
typedef __attribute__((ext_vector_type(8))) short s16x8;
typedef __attribute__((ext_vector_type(4))) short s16x4;

DI unsigned short f2h(float f) { return __half_as_ushort(__float2half(f)); }
DI float h2f(unsigned short u) { return __half2float(__ushort_as_half(u)); }

// operand-swapped: A-operand = weight fragment, B-operand = activation fragment.
// D: lane holds o = l4*4+r (4 consecutive channels), batch-row = l15.
#define MFMA16(A, B, C) (C) = __builtin_amdgcn_mfma_f32_16x16x32_f16((A), (B), (C), 0, 0, 0)

// ---------------------------------------------------------------------------
// Prep: weight-norm fold + diag-scale fold, emitting MFMA-FRAGMENT layout:
//   W'[kj][s][n16][lane(l4*16+l15)][8]; a wave's W-frag load = contiguous 1KB.
// ---------------------------------------------------------------------------
struct PrepArgs {
    const float *adj;
    const float *v0,*g0,*b0,*v1,*g1,*b1,*v2,*g2,*b2,*v3,*g3,*b3,*v4,*g4,*b4;
    unsigned short *w0,*w1,*w2,*w3;
    float *w4, *bias0,*bias1,*bias2,*bias3,*bias4;
};

template <int CIN, int CINPAD>
DI void prep_row(const float* __restrict__ v, const float* __restrict__ g,
                 const float* __restrict__ b, const float* __restrict__ adj,
                 int cout, int use_scale,
                 unsigned short* __restrict__ wout, float* __restrict__ biasout,
                 int ridx, int lane)
{
    const int k = ridx / cout;
    const int o = ridx - k * cout;
    const float* vr = v + (size_t)ridx * CIN;
    float xv[8];
    if (lane * 8 < CIN) {
        const f32x4 p0 = *reinterpret_cast<const f32x4*>(&vr[lane * 8]);
        const f32x4 p1 = *reinterpret_cast<const f32x4*>(&vr[lane * 8 + 4]);
        #pragma unroll
        for (int e = 0; e < 4; e++) { xv[e] = p0[e]; xv[4 + e] = p1[e]; }
    } else {
        #pragma unroll
        for (int e = 0; e < 8; e++) xv[e] = 0.f;
    }
    float ss = 0.f;
    #pragma unroll
    for (int e = 0; e < 8; e++) ss += xv[e] * xv[e];
    #pragma unroll
    for (int off = 32; off >= 1; off >>= 1) ss += __shfl_xor(ss, off, 64);
    float s = g[ridx] / sqrtf(ss);
    float bias = b[ridx];
    if (use_scale) {
        float d = adj[k * 81];            // adj[k][k]
        d = d > 0.f ? d : 0.f;
        s *= d; bias *= d;                // leaky(z)*s == leaky(z*s), s>=0
    }
    if (lane == 0) biasout[ridx] = bias;
    if (lane < CINPAD / 8) {
        unsigned short tmp[8];
        #pragma unroll
        for (int e = 0; e < 8; e++) tmp[e] = f2h(xv[e] * s);
        unsigned short* wj = wout + (size_t)k * cout * CINPAD;
        const int sblk = lane >> 2, l4w = lane & 3;
        const size_t pos = (((size_t)sblk * (cout >> 4) + (o >> 4)) * 64 + l4w * 16 + (o & 15)) * 8;
        *reinterpret_cast<s16x8*>(&wj[pos]) = *reinterpret_cast<const s16x8*>(tmp);
    }
}

DI void prep_w4_row(const float* __restrict__ v, const float* __restrict__ g,
                    const float* __restrict__ b, float* __restrict__ wout,
                    float* __restrict__ biasout, int ridx, int lane)
{
    const float x = v[(size_t)ridx * 64 + lane];
    float ss = x * x;
    #pragma unroll
    for (int off = 32; off >= 1; off >>= 1) ss += __shfl_xor(ss, off, 64);
    const float s = g[ridx] / sqrtf(ss);
    if (lane == 0) biasout[ridx] = b[ridx];
    wout[(size_t)ridx * 64 + lane] = x * s;
}

__global__ __launch_bounds__(256) void prep_kernel(PrepArgs a)
{
    const int bid = blockIdx.x, wave = threadIdx.x >> 6, lane = threadIdx.x & 63;
    if (bid < 10240)      prep_row<480, 512>(a.v0, a.g0, a.b0, a.adj, 512, 1, a.w0, a.bias0, bid * 4 + wave, lane);
    else if (bid < 15360) prep_row<512, 512>(a.v1, a.g1, a.b1, a.adj, 256, 1, a.w1, a.bias1, (bid - 10240) * 4 + wave, lane);
    else if (bid < 17920) prep_row<256, 256>(a.v2, a.g2, a.b2, a.adj, 128, 1, a.w2, a.bias2, (bid - 15360) * 4 + wave, lane);
    else if (bid < 19200) prep_row<128, 128>(a.v3, a.g3, a.b3, a.adj,  64, 0, a.w3, a.bias3, (bid - 17920) * 4 + wave, lane);
    else                  prep_w4_row(a.v4, a.g4, a.b4, a.w4, a.bias4, (bid - 19200) * 4 + wave, lane);
}

// ---------------------------------------------------------------------------
// Mega v8 (verified best, round 16): one block = 64 batch rows of one joint,
// 512 threads, single 64 KB in-place h-buffer (XOR chunk swizzle), fragment-
// layout W so every B load is a wave-coalesced 1KB read, 1-step W prefetch,
// operand-swapped MFMA (channel-major output -> b64 epilogue stores),
// fused RFF prologue, NT loads for pf.
// ---------------------------------------------------------------------------
struct MegaArgs {
    const float *qp, *pf, *Brff;
    const unsigned short *w0, *w1, *w2, *w3;
    const float *w4, *bias0, *bias1, *bias2, *bias3, *bias4;
    float* out;
};

__global__ __launch_bounds__(512, 4) void mega8_kernel(MegaArgs a)
{
    extern __shared__ __align__(16) unsigned short R0[];   // 32768 shorts = 64 KB
    const int tid = threadIdx.x, wid = tid >> 6, lane = tid & 63;
    const int l15 = lane & 15, l4 = lane >> 4;
    const int bid = blockIdx.x;
    const int swz = (bid & 7) * 320 + (bid >> 3);   // XCD-chunked, bijective (2560%8==0)
    const int kj = swz >> 5;
    const int m0 = (swz & 31) * 64;

    // ---- prologue: h0 = pf + RFF(qp)  -> R0 as [64][512] (480 real + 32 zero-pad)
    {
        const int row = tid >> 3;                 // 0..63
        const int tq  = tid & 7;
        const int gr  = (m0 + row) * 80 + kj;     // batch-major global row
        const float q0 = a.qp[gr * 3 + 0], q1 = a.qp[gr * 3 + 1], q2 = a.qp[gr * 3 + 2];
        #pragma unroll
        for (int i = 0; i < 8; i++) {
            const int c0 = tq * 8 + i * 64;       // multiples of 8, 0..504
            unsigned short o[8];
            if (c0 < 480) {
                const bool issin = (c0 >= 240);
                const int j0 = issin ? (c0 - 240) : c0;
                const f32x4 b0a = *reinterpret_cast<const f32x4*>(&a.Brff[j0]);
                const f32x4 b0b = *reinterpret_cast<const f32x4*>(&a.Brff[j0 + 4]);
                const f32x4 b1a = *reinterpret_cast<const f32x4*>(&a.Brff[240 + j0]);
                const f32x4 b1b = *reinterpret_cast<const f32x4*>(&a.Brff[240 + j0 + 4]);
                const f32x4 b2a = *reinterpret_cast<const f32x4*>(&a.Brff[480 + j0]);
                const f32x4 b2b = *reinterpret_cast<const f32x4*>(&a.Brff[480 + j0 + 4]);
                const f32x4 p0 = __builtin_nontemporal_load(
                    reinterpret_cast<const f32x4*>(&a.pf[(size_t)gr * 480 + c0]));
                const f32x4 p1 = __builtin_nontemporal_load(
                    reinterpret_cast<const f32x4*>(&a.pf[(size_t)gr * 480 + c0 + 4]));
                #pragma unroll
                for (int e = 0; e < 4; e++) {
                    float rev = q0 * b0a[e] + q1 * b1a[e] + q2 * b2a[e];
                    rev -= floorf(rev);           // v_sin/v_cos take revolutions
                    float t = issin ? __builtin_amdgcn_sinf(rev) : __builtin_amdgcn_cosf(rev);
                    o[e] = f2h(p0[e] + t);
                }
                #pragma unroll
                for (int e = 0; e < 4; e++) {
                    float rev = q0 * b0b[e] + q1 * b1b[e] + q2 * b2b[e];
                    rev -= floorf(rev);
                    float t = issin ? __builtin_amdgcn_sinf(rev) : __builtin_amdgcn_cosf(rev);
                    o[4 + e] = f2h(p1[e] + t);
                }
            } else {
                #pragma unroll
                for (int e = 0; e < 8; e++) o[e] = 0;
            }
            const int ck = c0 >> 3;
            *reinterpret_cast<s16x8*>(&R0[row * 512 + ((ck ^ (row & 7)) << 3)]) =
                *reinterpret_cast<const s16x8*>(o);
        }
    }
    __syncthreads();

    // ---- stage 0: h1 = leaky(h0 @ w0^T + b0).  N=512 (wave owns 64 cols), K=512.
    {
        const unsigned short* Wb = a.w0 + (size_t)kj * 262144 + (size_t)(wid * 4) * 512 + lane * 8;
        f32x4 acc[4][4] = {};
        f16x8 bfA[4], bfB[4];
        #pragma unroll
        for (int g = 0; g < 4; g++) bfA[g] = *reinterpret_cast<const f16x8*>(Wb + g * 512);
        #pragma unroll
        for (int ss = 0; ss < 8; ss++) {
            const int s0 = ss * 2, s1 = ss * 2 + 1;
            f16x8 af0[4];
            #pragma unroll
            for (int f = 0; f < 4; f++) {
                const int r = f * 16 + l15;
                af0[f] = *reinterpret_cast<const f16x8*>(&R0[r * 512 + (((s0 * 4 + l4) ^ (r & 7)) << 3)]);
            }
            #pragma unroll
            for (int g = 0; g < 4; g++)
                bfB[g] = *reinterpret_cast<const f16x8*>(Wb + (size_t)s1 * 16384 + g * 512);
            #pragma unroll
            for (int f = 0; f < 4; f++)
                #pragma unroll
                for (int g = 0; g < 4; g++)
                    MFMA16(bfA[g], af0[f], acc[f][g]);
            f16x8 af1[4];
            #pragma unroll
            for (int f = 0; f < 4; f++) {
                const int r = f * 16 + l15;
                af1[f] = *reinterpret_cast<const f16x8*>(&R0[r * 512 + (((s1 * 4 + l4) ^ (r & 7)) << 3)]);
            }
            if (ss < 7) {
                #pragma unroll
                for (int g = 0; g < 4; g++)
                    bfA[g] = *reinterpret_cast<const f16x8*>(Wb + (size_t)(s0 + 2) * 16384 + g * 512);
            }
            #pragma unroll
            for (int f = 0; f < 4; f++)
                #pragma unroll
                for (int g = 0; g < 4; g++)
                    MFMA16(bfB[g], af1[f], acc[f][g]);
        }
        __syncthreads();                          // all h0 reads done
        #pragma unroll
        for (int g = 0; g < 4; g++) {
            const f32x4 bv = *reinterpret_cast<const f32x4*>(
                &a.bias0[kj * 512 + wid * 64 + g * 16 + l4 * 4]);
            const int o = wid * 64 + g * 16 + l4 * 4;
            #pragma unroll
            for (int f = 0; f < 4; f++) {
                unsigned short o4[4];
                #pragma unroll
                for (int r = 0; r < 4; r++) {
                    float z = acc[f][g][r] + bv[r];
                    z = z >= 0.f ? z : 0.01f * z;
                    o4[r] = f2h(z);
                }
                const int row = f * 16 + l15;
                *reinterpret_cast<s16x4*>(
                    &R0[row * 512 + (((o >> 3) ^ (row & 7)) << 3) + (o & 7)]) =
                    *reinterpret_cast<const s16x4*>(o4);
            }
        }
    }
    __syncthreads();

    // ---- stage 1: h2 = leaky(h1 @ w1^T + b1).  N=256 (wave owns 32), K=512.
    {
        const unsigned short* Wb = a.w1 + (size_t)kj * 131072 + (size_t)(wid * 2) * 512 + lane * 8;
        f32x4 acc[4][2] = {};
        f16x8 bfA[2], bfB[2];
        #pragma unroll
        for (int g = 0; g < 2; g++) bfA[g] = *reinterpret_cast<const f16x8*>(Wb + g * 512);
        #pragma unroll
        for (int ss = 0; ss < 8; ss++) {
            const int s0 = ss * 2, s1 = ss * 2 + 1;
            f16x8 af0[4];
            #pragma unroll
            for (int f = 0; f < 4; f++) {
                const int r = f * 16 + l15;
                af0[f] = *reinterpret_cast<const f16x8*>(&R0[r * 512 + (((s0 * 4 + l4) ^ (r & 7)) << 3)]);
            }
            #pragma unroll
            for (int g = 0; g < 2; g++)
                bfB[g] = *reinterpret_cast<const f16x8*>(Wb + (size_t)s1 * 8192 + g * 512);
            #pragma unroll
            for (int f = 0; f < 4; f++)
                #pragma unroll
                for (int g = 0; g < 2; g++)
                    MFMA16(bfA[g], af0[f], acc[f][g]);
            f16x8 af1[4];
            #pragma unroll
            for (int f = 0; f < 4; f++) {
                const int r = f * 16 + l15;
                af1[f] = *reinterpret_cast<const f16x8*>(&R0[r * 512 + (((s1 * 4 + l4) ^ (r & 7)) << 3)]);
            }
            if (ss < 7) {
                #pragma unroll
                for (int g = 0; g < 2; g++)
                    bfA[g] = *reinterpret_cast<const f16x8*>(Wb + (size_t)(s0 + 2) * 8192 + g * 512);
            }
            #pragma unroll
            for (int f = 0; f < 4; f++)
                #pragma unroll
                for (int g = 0; g < 2; g++)
                    MFMA16(bfB[g], af1[f], acc[f][g]);
        }
        __syncthreads();
        #pragma unroll
        for (int g = 0; g < 2; g++) {
            const f32x4 bv = *reinterpret_cast<const f32x4*>(
                &a.bias1[kj * 256 + wid * 32 + g * 16 + l4 * 4]);
            const int o = wid * 32 + g * 16 + l4 * 4;
            #pragma unroll
            for (int f = 0; f < 4; f++) {
                unsigned short o4[4];
                #pragma unroll
                for (int r = 0; r < 4; r++) {
                    float z = acc[f][g][r] + bv[r];
                    z = z >= 0.f ? z : 0.01f * z;
                    o4[r] = f2h(z);
                }
                const int row = f * 16 + l15;
                *reinterpret_cast<s16x4*>(
                    &R0[row * 256 + (((o >> 3) ^ (row & 7)) << 3) + (o & 7)]) =
                    *reinterpret_cast<const s16x4*>(o4);
            }
        }
    }
    __syncthreads();

    // ---- stage 2: h3 = leaky(h2 @ w2^T + b2).  N=128 (wave owns 16), K=256.
    {
        const unsigned short* Wb = a.w2 + (size_t)kj * 32768 + (size_t)wid * 512 + lane * 8;
        f32x4 acc[4] = {};
        f16x8 bfA, bfB;
        bfA = *reinterpret_cast<const f16x8*>(Wb);
        #pragma unroll
        for (int ss = 0; ss < 4; ss++) {
            const int s0 = ss * 2, s1 = ss * 2 + 1;
            f16x8 af0[4];
            #pragma unroll
            for (int f = 0; f < 4; f++) {
                const int r = f * 16 + l15;
                af0[f] = *reinterpret_cast<const f16x8*>(&R0[r * 256 + (((s0 * 4 + l4) ^ (r & 7)) << 3)]);
            }
            bfB = *reinterpret_cast<const f16x8*>(Wb + (size_t)s1 * 4096);
            #pragma unroll
            for (int f = 0; f < 4; f++)
                MFMA16(bfA, af0[f], acc[f]);
            f16x8 af1[4];
            #pragma unroll
            for (int f = 0; f < 4; f++) {
                const int r = f * 16 + l15;
                af1[f] = *reinterpret_cast<const f16x8*>(&R0[r * 256 + (((s1 * 4 + l4) ^ (r & 7)) << 3)]);
            }
            if (ss < 3) bfA = *reinterpret_cast<const f16x8*>(Wb + (size_t)(s0 + 2) * 4096);
            #pragma unroll
            for (int f = 0; f < 4; f++)
                MFMA16(bfB, af1[f], acc[f]);
        }
        __syncthreads();
        {
            const f32x4 bv = *reinterpret_cast<const f32x4*>(
                &a.bias2[kj * 128 + wid * 16 + l4 * 4]);
            const int o = wid * 16 + l4 * 4;
            #pragma unroll
            for (int f = 0; f < 4; f++) {
                unsigned short o4[4];
                #pragma unroll
                for (int r = 0; r < 4; r++) {
                    float z = acc[f][r] + bv[r];
                    z = z >= 0.f ? z : 0.01f * z;
                    o4[r] = f2h(z);
                }
                const int row = f * 16 + l15;
                *reinterpret_cast<s16x4*>(
                    &R0[row * 128 + (((o >> 3) ^ (row & 7)) << 3) + (o & 7)]) =
                    *reinterpret_cast<const s16x4*>(o4);
            }
        }
    }
    __syncthreads();

    // ---- stage 3: h4 = leaky(h3 @ w3^T + b3).  N=64, K=128. Waves 2M x 4N.
    {
        const int wm = wid >> 2, wn4 = wid & 3;
        const unsigned short* Wb = a.w3 + (size_t)kj * 8192 + (size_t)wn4 * 512 + lane * 8;
        f32x4 acc[2] = {};
        #pragma unroll
        for (int s = 0; s < 4; s++) {
            f16x8 af[2], bf;
            #pragma unroll
            for (int f = 0; f < 2; f++) {
                const int r = wm * 32 + f * 16 + l15;
                af[f] = *reinterpret_cast<const f16x8*>(&R0[r * 128 + (((s * 4 + l4) ^ (r & 7)) << 3)]);
            }
            bf = *reinterpret_cast<const f16x8*>(Wb + (size_t)s * 2048);
            #pragma unroll
            for (int f = 0; f < 2; f++)
                MFMA16(bf, af[f], acc[f]);
        }
        __syncthreads();
        {
            const f32x4 bv = *reinterpret_cast<const f32x4*>(
                &a.bias3[kj * 64 + wn4 * 16 + l4 * 4]);
            const int o = wn4 * 16 + l4 * 4;
            #pragma unroll
            for (int f = 0; f < 2; f++) {
                unsigned short o4[4];
                #pragma unroll
                for (int r = 0; r < 4; r++) {
                    float z = acc[f][r] + bv[r];
                    z = z >= 0.f ? z : 0.01f * z;
                    o4[r] = f2h(z);
                }
                const int row = wm * 32 + f * 16 + l15;
                *reinterpret_cast<s16x4*>(
                    &R0[row * 64 + (((o >> 3) ^ (row & 7)) << 3) + (o & 7)]) =
                    *reinterpret_cast<const s16x4*>(o4);
            }
        }
    }
    __syncthreads();

    // ---- stage 4: out = h4 @ w4^T + b4 (f32, 6 outputs per row, NT stores).
    if (tid < 64) {
        const int row = tid;
        float xv[64];
        #pragma unroll
        for (int ch = 0; ch < 8; ch++) {
            s16x8 v = *reinterpret_cast<const s16x8*>(&R0[row * 64 + ((ch ^ (row & 7)) << 3)]);
            #pragma unroll
            for (int e = 0; e < 8; e++) xv[ch * 8 + e] = h2f((unsigned short)v[e]);
        }
        const float* w4b = a.w4 + kj * 384;
        float* op = a.out + ((size_t)(m0 + row) * 80 + kj) * 6;
        #pragma unroll
        for (int o = 0; o < 6; o++) {
            float sum = a.bias4[kj * 6 + o];
            #pragma unroll
            for (int i = 0; i < 64; i++) sum = fmaf(xv[i], w4b[o * 64 + i], sum);
            __builtin_nontemporal_store(sum, &op[o]);
        }
    }
}

// ---------------------------------------------------------------------------
extern "C" void kernel_launch(void* const* d_in, const int* in_sizes, int n_in,
                              void* d_out, int out_size, void* d_ws, size_t ws_size,
                              hipStream_t stream)
{
    (void)in_sizes; (void)n_in; (void)out_size; (void)ws_size;
    PrepArgs a;
    a.adj  = (const float*)d_in[2];
    a.v0 = (const float*)d_in[4];  a.g0 = (const float*)d_in[5];  a.b0 = (const float*)d_in[6];
    a.v1 = (const float*)d_in[7];  a.g1 = (const float*)d_in[8];  a.b1 = (const float*)d_in[9];
    a.v2 = (const float*)d_in[10]; a.g2 = (const float*)d_in[11]; a.b2 = (const float*)d_in[12];
    a.v3 = (const float*)d_in[13]; a.g3 = (const float*)d_in[14]; a.b3 = (const float*)d_in[15];
    a.v4 = (const float*)d_in[16]; a.g4 = (const float*)d_in[17]; a.b4 = (const float*)d_in[18];

    char* ws = (char*)d_ws;
    size_t off = 0;
    auto alloc = [&](size_t n) -> void* {
        off = (off + 255) & ~(size_t)255;
        void* p = ws + off;
        off += n;
        return p;
    };
    a.w0 = (unsigned short*)alloc(80ull * 512 * 512 * 2);
    a.w1 = (unsigned short*)alloc(80ull * 256 * 512 * 2);
    a.w2 = (unsigned short*)alloc(80ull * 128 * 256 * 2);
    a.w3 = (unsigned short*)alloc(80ull * 64 * 128 * 2);
    a.w4 = (float*)alloc(80ull * 6 * 64 * 4);
    a.bias0 = (float*)alloc(80ull * 512 * 4);
    a.bias1 = (float*)alloc(80ull * 256 * 4);
    a.bias2 = (float*)alloc(80ull * 128 * 4);
    a.bias3 = (float*)alloc(80ull * 64 * 4);
    a.bias4 = (float*)alloc(80ull * 6 * 4);

    MegaArgs m;
    m.qp   = (const float*)d_in[0];
    m.pf   = (const float*)d_in[1];
    m.Brff = (const float*)d_in[3];
    m.w0 = a.w0; m.w1 = a.w1; m.w2 = a.w2; m.w3 = a.w3; m.w4 = a.w4;
    m.bias0 = a.bias0; m.bias1 = a.bias1; m.bias2 = a.bias2;
    m.bias3 = a.bias3; m.bias4 = a.bias4;
    m.out = (float*)d_out;

    (void)hipFuncSetAttribute((const void*)mega8_kernel,
                              hipFuncAttributeMaxDynamicSharedMemorySize, 65536);

    prep_kernel<<<19320, 256, 0, stream>>>(a);
    mega8_kernel<<<2560, 512, 65536, stream>>>(m);
}